// Round 1
// baseline (159.303 us; speedup 1.0000x reference)
//
#include <hip/hip_runtime.h>

// Problem constants (fixed by the reference)
#define B_   64
#define S_   512
#define P_   300
#define K_   50
#define MPAD 64      // label dim padded to 64 for MFMA M
#define LDX  344     // x_tile row stride in bf16 elems (16B-aligned rows, bank-balanced)

typedef short short8v __attribute__((ext_vector_type(8)));
typedef float float4v __attribute__((ext_vector_type(4)));

__device__ __forceinline__ short f2bf(float f) {
  unsigned u = __builtin_bit_cast(unsigned, f);
  u = (u + 0x7FFFu + ((u >> 16) & 1u)) >> 16;  // RNE
  return (short)u;
}

// ---------------------------------------------------------------------------
// K1: normalize C -> l_hat, pad {l_hat, W2} to 64x320 bf16 (zeros), and pack
// into MFMA A-fragment order so K2's A loads are coalesced 16B/lane.
// apack layout: [(mat*4 + mtile)*10 + kstep][lane][8 bf16]
// grid 80 blocks (mat 2 x mtile 4 x kstep 10) x 64 threads.
// ---------------------------------------------------------------------------
__global__ __launch_bounds__(64) void k1_prep(const float* __restrict__ C,
                                              const float* __restrict__ W2,
                                              short* __restrict__ apack) {
  int bid = blockIdx.x;
  int mat = bid / 40;
  int rem = bid - mat * 40;
  int mt  = rem / 10;
  int ks  = rem - mt * 10;
  int lane = threadIdx.x;
  __shared__ float invn[16];
  if (mat == 0) {
    int rl = lane >> 2, q = lane & 3;
    int m = mt * 16 + rl;
    float ss = 0.f;
    if (m < K_) {
      for (int p = q; p < P_; p += 4) { float v = C[m * P_ + p]; ss += v * v; }
    }
    ss += __shfl_xor(ss, 1);
    ss += __shfl_xor(ss, 2);
    if (q == 0) invn[rl] = 1.f / (sqrtf(ss) + 0.001f);
  }
  __syncthreads();
  int ml = lane & 15, quad = lane >> 4;
  int m = mt * 16 + ml;
  const float* src = (mat == 0) ? C : W2;
  short8v v8;
  #pragma unroll
  for (int j = 0; j < 8; ++j) {
    int k = ks * 32 + quad * 8 + j;
    float v = 0.f;
    if (m < K_ && k < P_) {
      v = src[m * P_ + k];
      if (mat == 0) v *= invn[ml];
    }
    v8[j] = f2bf(v);
  }
  *(short8v*)(apack + (size_t)(((mat * 4 + mt) * 10 + ks) * 512 + lane * 8)) = v8;
}

// ---------------------------------------------------------------------------
// K2: per (b, 64-s chunk): gather emb rows -> LDS bf16 (f32 norms en route),
// dual GEMM via 16x16x32 bf16 MFMA:
//   G[b,m,s]  = (l_hat . x) * 1/(||x||+1e-3)   (scaled epilogue)
//   Yt[b,m,s] = (W2 . x)
// grid 512 x 256. Wave w owns M-rows [16w,16w+16).
// ---------------------------------------------------------------------------
__global__ __launch_bounds__(256) void k2_gemm(const int* __restrict__ idx,
                                               const float* __restrict__ emb,
                                               const short* __restrict__ apack,
                                               float* __restrict__ G,
                                               float* __restrict__ Yt) {
  __shared__ __align__(16) short xt[64][LDX];
  __shared__ float scale_s[64];
  int bid = blockIdx.x;
  int b = bid >> 3, s0 = (bid & 7) * 64;
  int tid = threadIdx.x;
  int w = tid >> 6, lane = tid & 63;

  // stage: wave w loads rows [16w, 16w+16)
  for (int r = 0; r < 16; ++r) {
    int ls = w * 16 + r;
    int row = idx[b * S_ + s0 + ls];
    const float4* src = (const float4*)(emb + (size_t)row * P_);
    float4 v = src[lane];                       // p = 4*lane .. 4*lane+3  (lanes 0..63 -> p<256)
    float ss = v.x * v.x + v.y * v.y + v.z * v.z + v.w * v.w;
    short4 h; h.x = f2bf(v.x); h.y = f2bf(v.y); h.z = f2bf(v.z); h.w = f2bf(v.w);
    *(short4*)&xt[ls][4 * lane] = h;
    if (lane < 11) {                            // p = 256..299
      float4 v2 = src[64 + lane];
      ss += v2.x * v2.x + v2.y * v2.y + v2.z * v2.z + v2.w * v2.w;
      short4 h2; h2.x = f2bf(v2.x); h2.y = f2bf(v2.y); h2.z = f2bf(v2.z); h2.w = f2bf(v2.w);
      *(short4*)&xt[ls][256 + 4 * lane] = h2;
    } else if (lane < 16) {                     // zero K-pad cols 300..319
      short4 z = {0, 0, 0, 0};
      *(short4*)&xt[ls][300 + 4 * (lane - 11)] = z;
    }
    #pragma unroll
    for (int off = 32; off > 0; off >>= 1) ss += __shfl_xor(ss, off);
    if (lane == 0) scale_s[ls] = 1.f / (sqrtf(ss) + 0.001f);
  }
  __syncthreads();

  float4v accG[4] = {}, accY[4] = {};
  int ml = lane & 15, quad = lane >> 4;
  const short8v* a1p = (const short8v*)(apack) + (size_t)((0 * 4 + w) * 10) * 64 + lane;
  const short8v* a2p = (const short8v*)(apack) + (size_t)((1 * 4 + w) * 10) * 64 + lane;
  #pragma unroll
  for (int ks = 0; ks < 10; ++ks) {
    short8v a1 = a1p[ks * 64];
    short8v a2 = a2p[ks * 64];
    int kk = ks * 32 + quad * 8;
    #pragma unroll
    for (int nt = 0; nt < 4; ++nt) {
      short8v bf = *(const short8v*)&xt[nt * 16 + ml][kk];
      accG[nt] = __builtin_amdgcn_mfma_f32_16x16x32_bf16(a1, bf, accG[nt], 0, 0, 0);
      accY[nt] = __builtin_amdgcn_mfma_f32_16x16x32_bf16(a2, bf, accY[nt], 0, 0, 0);
    }
  }

  // epilogue: C/D layout col = lane&15, row = quad*4+reg
  #pragma unroll
  for (int nt = 0; nt < 4; ++nt) {
    int sl = nt * 16 + ml;
    float sc = scale_s[sl];
    int sg = s0 + sl;
    #pragma unroll
    for (int reg = 0; reg < 4; ++reg) {
      int m = w * 16 + quad * 4 + reg;
      G [(size_t)(b * MPAD + m) * S_ + sg] = accG[nt][reg] * sc;
      Yt[(size_t)(b * MPAD + m) * S_ + sg] = accY[nt][reg];
    }
  }
}

// ---------------------------------------------------------------------------
// K3a: m[b,s] = max_{k<50} relu(conv11(G[b,k,s-5..s+5]) + conv_b)
// grid 512 x 256: block = (b, 64-s chunk), G chunk + halo staged in LDS.
// ---------------------------------------------------------------------------
__global__ __launch_bounds__(256) void k3a_conv(const float* __restrict__ G,
                                                const float* __restrict__ conv_w,
                                                const float* __restrict__ conv_b,
                                                float* __restrict__ mbuf) {
  __shared__ float gt[K_][76];
  __shared__ float mpart[4][64];
  int bid = blockIdx.x;
  int b = bid >> 3, s0 = (bid & 7) * 64;
  int tid = threadIdx.x;
  for (int e = tid; e < K_ * 74; e += 256) {
    int k = e / 74, i = e - k * 74;
    int s = s0 - 5 + i;
    gt[k][i] = (s >= 0 && s < S_) ? G[(size_t)(b * MPAD + k) * S_ + s] : 0.f;
  }
  float wv[11];
  #pragma unroll
  for (int t = 0; t < 11; ++t) wv[t] = conv_w[t];
  float cb = conv_b[0];
  __syncthreads();
  int sl = tid & 63, kg = tid >> 6;
  float mx = 0.f;  // relu outputs are >= 0, so 0 is a safe identity
  for (int k = kg; k < K_; k += 4) {
    float acc = cb;
    #pragma unroll
    for (int t = 0; t < 11; ++t) acc += wv[t] * gt[k][sl + t];
    mx = fmaxf(mx, fmaxf(acc, 0.f));
  }
  mpart[kg][sl] = mx;
  __syncthreads();
  if (tid < 64) {
    float m0 = fmaxf(fmaxf(mpart[0][tid], mpart[1][tid]),
                     fmaxf(mpart[2][tid], mpart[3][tid]));
    mbuf[b * S_ + s0 + tid] = m0;
  }
}

// ---------------------------------------------------------------------------
// K3b: per b: beta = softmax(m)/S; out[b,k] = sum_s beta_s * Yt[b,k,s] + b2[k]
// grid 64 x 512.
// ---------------------------------------------------------------------------
__global__ __launch_bounds__(512) void k3b_out(const float* __restrict__ mbuf,
                                               const float* __restrict__ Yt,
                                               const float* __restrict__ b2,
                                               float* __restrict__ out) {
  __shared__ float beta[S_];
  __shared__ float redm[8];
  __shared__ float reds[8];
  int b = blockIdx.x;
  int tid = threadIdx.x;
  int lane = tid & 63, wv = tid >> 6;
  float mv = mbuf[b * S_ + tid];
  float r = mv;
  #pragma unroll
  for (int off = 32; off > 0; off >>= 1) r = fmaxf(r, __shfl_xor(r, off));
  if (lane == 0) redm[wv] = r;
  __syncthreads();
  float bm = redm[0];
  #pragma unroll
  for (int i = 1; i < 8; ++i) bm = fmaxf(bm, redm[i]);
  float e = __expf(mv - bm);
  r = e;
  #pragma unroll
  for (int off = 32; off > 0; off >>= 1) r += __shfl_xor(r, off);
  if (lane == 0) reds[wv] = r;
  __syncthreads();
  float sum = 0.f;
  #pragma unroll
  for (int i = 0; i < 8; ++i) sum += reds[i];
  beta[tid] = e / (sum * (float)S_);   // fold the 1/S of jnp.mean into beta
  __syncthreads();
  for (int k = wv; k < K_; k += 8) {
    const float* yrow = Yt + (size_t)(b * MPAD + k) * S_;
    float acc = 0.f;
    #pragma unroll
    for (int i = 0; i < 8; ++i) {
      int s = lane + i * 64;
      acc += beta[s] * yrow[s];
    }
    #pragma unroll
    for (int off = 32; off > 0; off >>= 1) acc += __shfl_xor(acc, off);
    if (lane == 0) out[b * K_ + k] = acc + b2[k];
  }
}

// ---------------------------------------------------------------------------
extern "C" void kernel_launch(void* const* d_in, const int* in_sizes, int n_in,
                              void* d_out, int out_size, void* d_ws, size_t ws_size,
                              hipStream_t stream) {
  const int*   idx    = (const int*)  d_in[0];
  const float* emb    = (const float*)d_in[1];
  const float* C      = (const float*)d_in[2];
  const float* conv_w = (const float*)d_in[3];
  const float* conv_b = (const float*)d_in[4];
  const float* W2     = (const float*)d_in[5];
  const float* b2     = (const float*)d_in[6];
  float* out = (float*)d_out;

  char* ws = (char*)d_ws;
  // ws layout (bytes): apack 81920 | G 8388608 | Yt 8388608 | m 131072  (~16.2 MB)
  short* apack = (short*)(ws);
  float* G     = (float*)(ws + 81920);
  float* Yt    = (float*)(ws + 81920 + 8388608);
  float* mbuf  = (float*)(ws + 81920 + 2 * 8388608);

  hipLaunchKernelGGL(k1_prep, dim3(80),  dim3(64),  0, stream, C, W2, apack);
  hipLaunchKernelGGL(k2_gemm, dim3(512), dim3(256), 0, stream, idx, emb, apack, G, Yt);
  hipLaunchKernelGGL(k3a_conv, dim3(512), dim3(256), 0, stream, G, conv_w, conv_b, mbuf);
  hipLaunchKernelGGL(k3b_out, dim3(64),  dim3(512), 0, stream, mbuf, Yt, b2, out);
}